// Round 7
// baseline (116.503 us; speedup 1.0000x reference)
//
#include <hip/hip_runtime.h>
#include <hip/hip_bf16.h>
#include <math.h>

// Fused ConvTranspose2d(64->64,k4,s2,p1) + BN + softmax(C) + maxpool2x2 via bf16 MFMA.
//
// R14: R13 + latency-hiding in the ks loop (R13: 43.3us, pipe-busy sum 47%,
// a-frag ds_read_b128 latency ~120cy fully exposed each of 8 ks-steps):
//  - af double-buffer: issue ks+1's two ds_read_b128 BEFORE ks's 8 MFMAs
//    (~155cy) -> LDS latency hidden; compiler emits counted lgkmcnt.
//  - xs padded to 66 cols (zero cols 0/65): kills all and8 edge masks and
//    the &63 wrap (~64 v_and = 128cy/wave). LDS xs = 25344B.
//  - launch_bounds(512,4): 128-reg cap fits acc32+bf32+af16+addr (~100 live)
//    without spill; 2 blocks/CU = what R13 actually achieved anyway.
// Kept from R13: class-per-wave (reads only its own 32KB g_wfrag slice),
// red[64][65] pitch-65 ds_max_u32 pooling, XCD-grouping ph swizzle
// (FETCH 51->20.5MB), BN bias as MFMA C-in, log2e folded into weights,
// DPP 16-lane softmax reduce, v_cvt_pk_bf16_f32 staging.

typedef __attribute__((ext_vector_type(8))) short short8;
typedef __attribute__((ext_vector_type(4))) float floatx4;
typedef __attribute__((ext_vector_type(2))) unsigned uint2v;

__device__ ushort g_wfrag[4 * 8 * 4 * 64 * 8];  // [class][ks][nt][lane][j], 128 KB
__device__ float g_aff[64];  // ((bias-mean)*A + beta) * log2e

#define L2E 1.44269504088896340736f

__device__ __forceinline__ ushort f2bf(float f) {
  union { float f; unsigned u; } v; v.f = f;
  unsigned r = v.u + 0x7FFF + ((v.u >> 16) & 1);  // RNE
  return (ushort)(r >> 16);
}

// prep: thread = (cin pair, cout). BN scale A and log2(e) folded into weights.
__global__ __launch_bounds__(256) void prep_kernel(
    const float* __restrict__ w, const float* __restrict__ bias,
    const float* __restrict__ gamma, const float* __restrict__ beta,
    const float* __restrict__ mean, const float* __restrict__ var) {
  int t = blockIdx.x * 256 + threadIdx.x;  // 0..2047
  int cin0 = (t >> 6) * 2;                 // even cin
  int cout = t & 63;
  int nt = cout >> 4, b15 = cout & 15;
  int q = (cin0 & 31) >> 3;                // quad within k-step
  int j = cin0 & 7;                        // j within quad (even)
  int ksq = cin0 >> 5;                     // which 32-block within tap
  float Aw = gamma[cout] * rsqrtf(var[cout] + 1e-5f) * L2E;

  const float4* p0 = (const float4*)&w[(cin0 * 64 + cout) * 16];
  const float4* p1 = (const float4*)&w[((cin0 + 1) * 64 + cout) * 16];
  float a[16], b[16];
  {
    float4 f0 = p0[0], f1 = p0[1], f2 = p0[2], f3 = p0[3];
    a[0]=f0.x; a[1]=f0.y; a[2]=f0.z; a[3]=f0.w; a[4]=f1.x; a[5]=f1.y; a[6]=f1.z; a[7]=f1.w;
    a[8]=f2.x; a[9]=f2.y; a[10]=f2.z; a[11]=f2.w; a[12]=f3.x; a[13]=f3.y; a[14]=f3.z; a[15]=f3.w;
    float4 g0 = p1[0], g1 = p1[1], g2 = p1[2], g3 = p1[3];
    b[0]=g0.x; b[1]=g0.y; b[2]=g0.z; b[3]=g0.w; b[4]=g1.x; b[5]=g1.y; b[6]=g1.z; b[7]=g1.w;
    b[8]=g2.x; b[9]=g2.y; b[10]=g2.z; b[11]=g2.w; b[12]=g3.x; b[13]=g3.y; b[14]=g3.z; b[15]=g3.w;
  }
#pragma unroll
  for (int kh = 0; kh < 4; ++kh)
#pragma unroll
    for (int kw = 0; kw < 4; ++kw) {
      int r = (kh & 1) ? 0 : 1;
      int pp = (kw & 1) ? 0 : 1;
      int c = r * 2 + pp;
      int tap = (kh >> 1) * 2 + (kw >> 1);
      int ks = tap * 2 + ksq;
      unsigned u = (unsigned)f2bf(a[kh * 4 + kw] * Aw) |
                   ((unsigned)f2bf(b[kh * 4 + kw] * Aw) << 16);
      *(unsigned*)&g_wfrag[(((c * 8 + ks) * 4 + nt) * 64 + q * 16 + b15) * 8 + j] = u;
    }

  if (t < 64) {
    float A0 = gamma[t] * rsqrtf(var[t] + 1e-5f);
    g_aff[t] = ((bias[t] - mean[t]) * A0 + beta[t]) * L2E;
  }
}

__device__ __forceinline__ unsigned cvtpk(float a, float b) {
  unsigned r;
  asm("v_cvt_pk_bf16_f32 %0, %1, %2" : "=v"(r) : "v"(a), "v"(b));
  return r;
}

template <int CTRL>
__device__ __forceinline__ float dpp_add(float v) {
  unsigned t = (unsigned)__builtin_amdgcn_update_dpp(
      0, (int)__float_as_uint(v), CTRL, 0xF, 0xF, true);
  return v + __uint_as_float(t);
}

// sum across each 16-lane group (lanes differing in bits 0..3), result in all
// lanes, pure-VALU via DPP: quad_perm xor1, xor2, row_half_mirror, row_mirror.
__device__ __forceinline__ float sum16(float v) {
  v = dpp_add<0xB1>(v);   // quad_perm [1,0,3,2]  (xor 1)
  v = dpp_add<0x4E>(v);   // quad_perm [2,3,0,1]  (xor 2)
  v = dpp_add<0x141>(v);  // row_half_mirror      (xor 4)
  v = dpp_add<0x140>(v);  // row_mirror           (xor 8)
  return v;
}

__device__ __forceinline__ float fexp2(float x) {
#if __has_builtin(__builtin_amdgcn_exp2f)
  return __builtin_amdgcn_exp2f(x);
#else
  return exp2f(x);
#endif
}

#define COLS 66
#define ROWSTRIDE (COLS * 64)  // 4224 ushorts per halo row

__global__ __launch_bounds__(512, 4) void fused_kernel(const float* __restrict__ x,
                                                       float* __restrict__ out) {
  __shared__ __align__(16) ushort xs[3 * ROWSTRIDE];  // 25344 B halo, swizzled+padded
  __shared__ __align__(16) float red[64 * 65 + 16];   // 16704 B pooled-max, pitch 65

  const int tid  = threadIdx.x;
  // XCD-grouping: consecutive ph (sharing 2/3 halo rows) -> same XCD L2
  const int ph   = ((blockIdx.x & 7) << 3) | (blockIdx.x >> 3);  // bijective on [0,64)
  const int n    = blockIdx.y;
  const int wave = tid >> 6;
  const int lane = tid & 63;
  const int b15  = lane & 15;
  const int q    = lane >> 4;
  const int wc   = wave & 1;   // col half (32 cols)
  const int c    = wave >> 1;  // parity class (r,p)
  const int r    = c >> 1, p = c & 1;

  // ---- zero the pooled-max buffer (covered by the staging barrier) ----
  {
    float4 z = {0.f, 0.f, 0.f, 0.f};
    for (int e = tid; e < 1044; e += 512) ((float4*)red)[e] = z;
  }

  // ---- stage x halo rows ph-1..ph+1, swizzled [row][col+1][chunk^(col&7)] ----
  for (int e = tid; e < 768; e += 512) {
    int iw4 = e & 15;          // group of 4 iw
    int c4  = (e >> 4) & 15;   // group of 4 cin
    int row = e >> 8;          // 0..2
    int ih  = ph - 1 + row;
    float4 v0 = {0.f, 0.f, 0.f, 0.f}, v1 = v0, v2 = v0, v3 = v0;
    if (ih >= 0 && ih < 64) {
      const float* xp = x + ((n * 64 + c4 * 4) * 64 + ih) * 64 + iw4 * 4;
      v0 = *(const float4*)xp;          v1 = *(const float4*)(xp + 4096);
      v2 = *(const float4*)(xp + 8192); v3 = *(const float4*)(xp + 12288);
    }
    int chunk = c4 >> 1, half4 = (c4 & 1) * 4;
    float cc[4][4] = {{v0.x, v1.x, v2.x, v3.x}, {v0.y, v1.y, v2.y, v3.y},
                      {v0.z, v1.z, v2.z, v3.z}, {v0.w, v1.w, v2.w, v3.w}};
#pragma unroll
    for (int ii = 0; ii < 4; ++ii) {
      int col = iw4 * 4 + ii + 1;
      uint2v pk = {cvtpk(cc[ii][0], cc[ii][1]), cvtpk(cc[ii][2], cc[ii][3])};
      *(uint2v*)&xs[(row * COLS + col) * 64 + ((chunk ^ (col & 7)) * 8) + half4] = pk;
    }
  }
  // zero-pad cols 0 and 65 (all chunks)
  for (int e = tid; e < 96; e += 512) {
    int c4 = e & 15, side = (e >> 4) & 1, row = e >> 5;
    int col = side ? 65 : 0;
    int chunk = c4 >> 1, half4 = (c4 & 1) * 4;
    ushort4 z; z.x = z.y = z.z = z.w = 0;
    *(ushort4*)&xs[(row * COLS + col) * 64 + ((chunk ^ (col & 7)) * 8) + half4] = z;
  }

  // BN bias (already * log2e) -> MFMA C-in
  float Dc[4];
#pragma unroll
  for (int nt = 0; nt < 4; ++nt) Dc[nt] = g_aff[nt * 16 + b15];

  // a-frag LDS addresses (ushort idx), [mt][b][par]; padded col, no masks
  int A_[2][2][2];
#pragma unroll
  for (int mt = 0; mt < 2; ++mt)
#pragma unroll
    for (int b = 0; b < 2; ++b) {
      int col = wc * 32 + mt * 16 + b15 + (b ? p - 1 : p) + 1;  // 0..65
#pragma unroll
      for (int par = 0; par < 2; ++par)
        A_[mt][b][par] = r * ROWSTRIDE + col * 64 + (((par * 4 + q) ^ (col & 7)) * 8);
    }

  // first b-frag load issued before the barrier (independent of LDS)
  short8 bfA[4], bfB[4];
  {
    const short8* wf = (const short8*)g_wfrag + (c * 8) * 256;
#pragma unroll
    for (int nt = 0; nt < 4; ++nt) bfA[nt] = wf[nt * 64 + lane];
  }
  __syncthreads();

  floatx4 acc[8];  // [mt*4+nt], C-in = BN bias
#pragma unroll
  for (int nt = 0; nt < 4; ++nt) {
    acc[nt]     = (floatx4){Dc[nt], Dc[nt], Dc[nt], Dc[nt]};
    acc[4 + nt] = (floatx4){Dc[nt], Dc[nt], Dc[nt], Dc[nt]};
  }

  // af double-buffer: issue ks+1's ds_reads before ks's MFMAs
  short8 afA[2], afB[2];
#define AF_READ(dst, ks_)                                                     \
  {                                                                           \
    const int b_ = ((ks_) >> 1) & 1, par_ = (ks_)&1;                          \
    const int ho_ = ((ks_) >> 2) ? 0 : ROWSTRIDE;                             \
    dst[0] = *(const short8*)&xs[A_[0][b_][par_] + ho_];                      \
    dst[1] = *(const short8*)&xs[A_[1][b_][par_] + ho_];                      \
  }
  AF_READ(afA, 0);

#pragma unroll
  for (int ks = 0; ks < 8; ++ks) {
    short8* bcur = (ks & 1) ? bfB : bfA;
    short8* bnxt = (ks & 1) ? bfA : bfB;
    if (ks < 7) {  // prefetch next ks's weights (in flight across the MFMAs)
      const short8* wf = (const short8*)g_wfrag + (c * 8 + ks + 1) * 256;
#pragma unroll
      for (int nt = 0; nt < 4; ++nt) bnxt[nt] = wf[nt * 64 + lane];
    }
    short8* acur = (ks & 1) ? afB : afA;
    short8* anxt = (ks & 1) ? afA : afB;
    if (ks < 7) {
      if (ks == 0) AF_READ(anxt, 1);
      if (ks == 1) AF_READ(anxt, 2);
      if (ks == 2) AF_READ(anxt, 3);
      if (ks == 3) AF_READ(anxt, 4);
      if (ks == 4) AF_READ(anxt, 5);
      if (ks == 5) AF_READ(anxt, 6);
      if (ks == 6) AF_READ(anxt, 7);
    }
#pragma unroll
    for (int nt = 0; nt < 4; ++nt) {
      acc[nt]     = __builtin_amdgcn_mfma_f32_16x16x32_bf16(acur[0], bcur[nt], acc[nt], 0, 0, 0);
      acc[4 + nt] = __builtin_amdgcn_mfma_f32_16x16x32_bf16(acur[1], bcur[nt], acc[4 + nt], 0, 0, 0);
    }
  }

  // ---- softmax (exp2 of pre-scaled logits) + cross-class maxpool via ds_max_u32 ----
  // (softmax outputs > 0 -> float bit pattern is order-preserving as unsigned)
#pragma unroll
  for (int mt = 0; mt < 2; ++mt) {
    float sm[4] = {0.f, 0.f, 0.f, 0.f};
#pragma unroll
    for (int nt = 0; nt < 4; ++nt)
#pragma unroll
      for (int reg = 0; reg < 4; ++reg) {
        float e = fexp2(acc[mt * 4 + nt][reg]);
        acc[mt * 4 + nt][reg] = e;
        sm[reg] += e;
      }
#pragma unroll
    for (int reg = 0; reg < 4; ++reg)
      sm[reg] = __builtin_amdgcn_rcpf(sum16(sm[reg]));
#pragma unroll
    for (int nt = 0; nt < 4; ++nt) {
      int idx = (nt * 16 + b15) * 65 + wc * 32 + mt * 16 + q * 4;
#pragma unroll
      for (int reg = 0; reg < 4; ++reg) {
        float v = acc[mt * 4 + nt][reg] * sm[reg];
        __hip_atomic_fetch_max((unsigned*)&red[idx + reg], __float_as_uint(v),
                               __ATOMIC_RELAXED, __HIP_MEMORY_SCOPE_WORKGROUP);
      }
    }
  }
  __syncthreads();

  // ---- coalesced stores ----
  for (int e = tid; e < 2048; e += 512) {
    int pw2  = e & 31;
    int cout = e >> 5;
    int base = cout * 65 + pw2 * 2;
    float2 val = {red[base], red[base + 1]};
    *(float2*)&out[((n * 64 + cout) * 64 + ph) * 64 + pw2 * 2] = val;
  }
}

extern "C" void kernel_launch(void* const* d_in, const int* in_sizes, int n_in,
                              void* d_out, int out_size, void* d_ws, size_t ws_size,
                              hipStream_t stream) {
  const float* x     = (const float*)d_in[0];
  const float* w     = (const float*)d_in[1];
  const float* bias  = (const float*)d_in[2];
  const float* gamma = (const float*)d_in[3];
  const float* beta  = (const float*)d_in[4];
  const float* mean  = (const float*)d_in[5];
  const float* var   = (const float*)d_in[6];
  float* out = (float*)d_out;

  prep_kernel<<<8, 256, 0, stream>>>(w, bias, gamma, beta, mean, var);
  dim3 grid(64, 32);  // (pooled row [XCD-swizzled], n)
  fused_kernel<<<grid, 512, 0, stream>>>(x, out);
}

// Round 8
// 112.582 us; speedup vs baseline: 1.0348x; 1.0348x over previous
//
#include <hip/hip_runtime.h>
#include <hip/hip_bf16.h>
#include <math.h>

// Fused ConvTranspose2d(64->64,k4,s2,p1) + BN + softmax(C) + maxpool2x2 via bf16 MFMA.
//
// R15: attack per-block-scaled costs (R14: fused ~42us, all pipes <50%,
// 512MB of L2 weight re-reads = ~15us + ~225cy latency each ks, 2048 blocks
// paying fixed staging/epilogue costs):
//  - weights staged to LDS via global_load_lds (16B/lane, fire-and-forget),
//    double-buffered wbuf[2][16seg][1KB]; wave (c,wc) stages its class's
//    nt=2wc,2wc+1 for ks+1 at top of iteration ks; one __syncthreads per ks
//    (implicit vmcnt+lgkm drain = exactly the required semantics). Each
//    weight byte read from L2 ONCE per block (wave-pair sharing via LDS).
//  - 2 pooled rows per block (grid 32x32, 4-row halo): weight L2 traffic
//    512->128MB, halo redundancy 3x->2x, per-block fixed costs amortized.
//    acc[16] fits now: bf regs freed by LDS weights (acc64+af16+bf8+addr
//    ~110 < 128) -> no R11-style spill at (512,4).
//  - red[2][64][65] overlaid on xs (dead after last ks barrier):
//    LDS = 33792(xs) + 32768(wbuf) = 66560 -> 2 blocks/CU.
// Kept: class-per-wave, pitch-65 ds_max_u32 pooling, XCD-grouping swizzle,
// BN bias as MFMA C-in, log2e folded into weights, padded 66-col halo
// (no edge masks), DPP 16-lane softmax reduce, v_cvt_pk_bf16_f32 staging.

typedef __attribute__((ext_vector_type(8))) short short8;
typedef __attribute__((ext_vector_type(4))) float floatx4;
typedef __attribute__((ext_vector_type(2))) unsigned uint2v;

__device__ ushort g_wfrag[4 * 8 * 4 * 64 * 8];  // [class][ks][nt][lane][j], 128 KB
__device__ float g_aff[64];  // ((bias-mean)*A + beta) * log2e

#define L2E 1.44269504088896340736f

__device__ __forceinline__ ushort f2bf(float f) {
  union { float f; unsigned u; } v; v.f = f;
  unsigned r = v.u + 0x7FFF + ((v.u >> 16) & 1);  // RNE
  return (ushort)(r >> 16);
}

// prep: thread = (cin pair, cout). BN scale A and log2(e) folded into weights.
__global__ __launch_bounds__(256) void prep_kernel(
    const float* __restrict__ w, const float* __restrict__ bias,
    const float* __restrict__ gamma, const float* __restrict__ beta,
    const float* __restrict__ mean, const float* __restrict__ var) {
  int t = blockIdx.x * 256 + threadIdx.x;  // 0..2047
  int cin0 = (t >> 6) * 2;                 // even cin
  int cout = t & 63;
  int nt = cout >> 4, b15 = cout & 15;
  int q = (cin0 & 31) >> 3;                // quad within k-step
  int j = cin0 & 7;                        // j within quad (even)
  int ksq = cin0 >> 5;                     // which 32-block within tap
  float Aw = gamma[cout] * rsqrtf(var[cout] + 1e-5f) * L2E;

  const float4* p0 = (const float4*)&w[(cin0 * 64 + cout) * 16];
  const float4* p1 = (const float4*)&w[((cin0 + 1) * 64 + cout) * 16];
  float a[16], b[16];
  {
    float4 f0 = p0[0], f1 = p0[1], f2 = p0[2], f3 = p0[3];
    a[0]=f0.x; a[1]=f0.y; a[2]=f0.z; a[3]=f0.w; a[4]=f1.x; a[5]=f1.y; a[6]=f1.z; a[7]=f1.w;
    a[8]=f2.x; a[9]=f2.y; a[10]=f2.z; a[11]=f2.w; a[12]=f3.x; a[13]=f3.y; a[14]=f3.z; a[15]=f3.w;
    float4 g0 = p1[0], g1 = p1[1], g2 = p1[2], g3 = p1[3];
    b[0]=g0.x; b[1]=g0.y; b[2]=g0.z; b[3]=g0.w; b[4]=g1.x; b[5]=g1.y; b[6]=g1.z; b[7]=g1.w;
    b[8]=g2.x; b[9]=g2.y; b[10]=g2.z; b[11]=g2.w; b[12]=g3.x; b[13]=g3.y; b[14]=g3.z; b[15]=g3.w;
  }
#pragma unroll
  for (int kh = 0; kh < 4; ++kh)
#pragma unroll
    for (int kw = 0; kw < 4; ++kw) {
      int r = (kh & 1) ? 0 : 1;
      int pp = (kw & 1) ? 0 : 1;
      int c = r * 2 + pp;
      int tap = (kh >> 1) * 2 + (kw >> 1);
      int ks = tap * 2 + ksq;
      unsigned u = (unsigned)f2bf(a[kh * 4 + kw] * Aw) |
                   ((unsigned)f2bf(b[kh * 4 + kw] * Aw) << 16);
      *(unsigned*)&g_wfrag[(((c * 8 + ks) * 4 + nt) * 64 + q * 16 + b15) * 8 + j] = u;
    }

  if (t < 64) {
    float A0 = gamma[t] * rsqrtf(var[t] + 1e-5f);
    g_aff[t] = ((bias[t] - mean[t]) * A0 + beta[t]) * L2E;
  }
}

__device__ __forceinline__ unsigned cvtpk(float a, float b) {
  unsigned r;
  asm("v_cvt_pk_bf16_f32 %0, %1, %2" : "=v"(r) : "v"(a), "v"(b));
  return r;
}

template <int CTRL>
__device__ __forceinline__ float dpp_add(float v) {
  unsigned t = (unsigned)__builtin_amdgcn_update_dpp(
      0, (int)__float_as_uint(v), CTRL, 0xF, 0xF, true);
  return v + __uint_as_float(t);
}

// sum across each 16-lane group, result in all lanes, pure-VALU via DPP.
__device__ __forceinline__ float sum16(float v) {
  v = dpp_add<0xB1>(v);   // quad_perm [1,0,3,2]  (xor 1)
  v = dpp_add<0x4E>(v);   // quad_perm [2,3,0,1]  (xor 2)
  v = dpp_add<0x141>(v);  // row_half_mirror      (xor 4)
  v = dpp_add<0x140>(v);  // row_mirror           (xor 8)
  return v;
}

__device__ __forceinline__ float fexp2(float x) {
#if __has_builtin(__builtin_amdgcn_exp2f)
  return __builtin_amdgcn_exp2f(x);
#else
  return exp2f(x);
#endif
}

__device__ __forceinline__ void gload_lds16(const void* g, void* l) {
  __builtin_amdgcn_global_load_lds(
      (const __attribute__((address_space(1))) void*)g,
      (__attribute__((address_space(3))) void*)l, 16, 0, 0);
}

#define COLS 66
#define ROWSTRIDE (COLS * 64)  // 4224 ushorts per halo row

__global__ __launch_bounds__(512, 4) void fused_kernel(const float* __restrict__ x,
                                                       float* __restrict__ out) {
  __shared__ __align__(16) ushort xs[4 * ROWSTRIDE];    // 33792 B halo; reused as red
  __shared__ __align__(16) ushort wbuf[2 * 16 * 512];   // 32768 B weight dbuf

  const int tid  = threadIdx.x;
  // XCD-grouping: consecutive ph-pairs (sharing halo rows) -> same XCD L2
  const int swz  = ((blockIdx.x & 7) << 2) | (blockIdx.x >> 3);  // bijective on [0,32)
  const int ph0  = swz * 2;
  const int n    = blockIdx.y;
  const int wave = tid >> 6;
  const int lane = tid & 63;
  const int b15  = lane & 15;
  const int q    = lane >> 4;
  const int wc   = wave & 1;   // col half (32 cols)
  const int c    = wave >> 1;  // parity class (r,p)
  const int r    = c >> 1, p = c & 1;

  // stage wbuf[0] (ks=0) first: L2 latency hides under the halo staging
#define STAGE_W(buf_, ksrc_)                                                      \
  {                                                                               \
    const int nt0_ = 2 * wc;                                                      \
    gload_lds16(&g_wfrag[(((c * 8 + (ksrc_)) * 4 + nt0_) * 64 + lane) * 8],       \
                &wbuf[((buf_) * 16 + c * 4 + nt0_) * 512]);                       \
    gload_lds16(&g_wfrag[(((c * 8 + (ksrc_)) * 4 + nt0_ + 1) * 64 + lane) * 8],   \
                &wbuf[((buf_) * 16 + c * 4 + nt0_ + 1) * 512]);                   \
  }
  STAGE_W(0, 0);

  // ---- stage x halo rows ph0-1..ph0+2, swizzled [row][col+1][chunk^(col&7)] ----
  for (int e = tid; e < 1024; e += 512) {
    int iw4 = e & 15;          // group of 4 iw
    int c4  = (e >> 4) & 15;   // group of 4 cin
    int row = e >> 8;          // 0..3
    int ih  = ph0 - 1 + row;
    float4 v0 = {0.f, 0.f, 0.f, 0.f}, v1 = v0, v2 = v0, v3 = v0;
    if (ih >= 0 && ih < 64) {
      const float* xp = x + ((n * 64 + c4 * 4) * 64 + ih) * 64 + iw4 * 4;
      v0 = *(const float4*)xp;          v1 = *(const float4*)(xp + 4096);
      v2 = *(const float4*)(xp + 8192); v3 = *(const float4*)(xp + 12288);
    }
    int chunk = c4 >> 1, half4 = (c4 & 1) * 4;
    float cc[4][4] = {{v0.x, v1.x, v2.x, v3.x}, {v0.y, v1.y, v2.y, v3.y},
                      {v0.z, v1.z, v2.z, v3.z}, {v0.w, v1.w, v2.w, v3.w}};
#pragma unroll
    for (int ii = 0; ii < 4; ++ii) {
      int col = iw4 * 4 + ii + 1;
      uint2v pk = {cvtpk(cc[ii][0], cc[ii][1]), cvtpk(cc[ii][2], cc[ii][3])};
      *(uint2v*)&xs[(row * COLS + col) * 64 + ((chunk ^ (col & 7)) * 8) + half4] = pk;
    }
  }
  // zero-pad cols 0 and 65 (all 4 rows, all chunks)
  for (int e = tid; e < 128; e += 512) {
    int c4 = e & 15, side = (e >> 4) & 1, row = e >> 5;
    int col = side ? 65 : 0;
    int chunk = c4 >> 1, half4 = (c4 & 1) * 4;
    ushort4 z; z.x = z.y = z.z = z.w = 0;
    *(ushort4*)&xs[(row * COLS + col) * 64 + ((chunk ^ (col & 7)) * 8) + half4] = z;
  }

  // BN bias (already * log2e) -> MFMA C-in
  float Dc[4];
#pragma unroll
  for (int nt = 0; nt < 4; ++nt) Dc[nt] = g_aff[nt * 16 + b15];

  // a-frag LDS addresses (ushort idx), [mt][b][par]; padded col, no masks.
  // total row = r + prow + 1 - a; r folded into A_, (prow+1-a)*RS added per read.
  int A_[2][2][2];
#pragma unroll
  for (int mt = 0; mt < 2; ++mt)
#pragma unroll
    for (int b = 0; b < 2; ++b) {
      int col = wc * 32 + mt * 16 + b15 + (b ? p - 1 : p) + 1;  // 0..65
#pragma unroll
      for (int par = 0; par < 2; ++par)
        A_[mt][b][par] = r * ROWSTRIDE + col * 64 + (((par * 4 + q) ^ (col & 7)) * 8);
    }

  __syncthreads();  // drains wbuf[0] staging (vmcnt) + xs writes (lgkm)

  floatx4 acc[16];  // [prow*8 + mt*4 + nt], C-in = BN bias
#pragma unroll
  for (int i = 0; i < 16; ++i) {
    float d = Dc[i & 3];
    acc[i] = (floatx4){d, d, d, d};
  }

#pragma unroll
  for (int ks = 0; ks < 8; ++ks) {
    const int cur = ks & 1;
    if (ks < 7) STAGE_W(cur ^ 1, ks + 1);  // async, in flight across the MFMAs
    const int b_ = (ks >> 1) & 1, par_ = ks & 1;
    const int ro = (ks >> 2) ? 0 : ROWSTRIDE;  // (1-a)*RS
    short8 af00 = *(const short8*)&xs[A_[0][b_][par_] + ro];              // prow0 mt0
    short8 af01 = *(const short8*)&xs[A_[1][b_][par_] + ro];              // prow0 mt1
    short8 af10 = *(const short8*)&xs[A_[0][b_][par_] + ro + ROWSTRIDE];  // prow1 mt0
    short8 af11 = *(const short8*)&xs[A_[1][b_][par_] + ro + ROWSTRIDE];  // prow1 mt1
#pragma unroll
    for (int nt = 0; nt < 4; ++nt) {
      short8 bf = *(const short8*)&wbuf[((cur * 16 + c * 4 + nt) * 64 + lane) * 8];
      acc[nt]      = __builtin_amdgcn_mfma_f32_16x16x32_bf16(af00, bf, acc[nt], 0, 0, 0);
      acc[4 + nt]  = __builtin_amdgcn_mfma_f32_16x16x32_bf16(af01, bf, acc[4 + nt], 0, 0, 0);
      acc[8 + nt]  = __builtin_amdgcn_mfma_f32_16x16x32_bf16(af10, bf, acc[8 + nt], 0, 0, 0);
      acc[12 + nt] = __builtin_amdgcn_mfma_f32_16x16x32_bf16(af11, bf, acc[12 + nt], 0, 0, 0);
    }
    __syncthreads();  // stage(ks+1) complete + all reads of wbuf[cur]/xs done
  }

  // ---- xs is dead: overlay red[2][64][65] f32 on it ----
  float* red = (float*)xs;
  {
    float4 z = {0.f, 0.f, 0.f, 0.f};
    for (int e = tid; e < 2080; e += 512) ((float4*)red)[e] = z;  // 33280 B
  }
  __syncthreads();

  // ---- softmax (exp2 of pre-scaled logits) + cross-class maxpool via ds_max_u32 ----
  // (softmax outputs > 0 -> float bit pattern is order-preserving as unsigned)
#pragma unroll
  for (int prow = 0; prow < 2; ++prow)
#pragma unroll
    for (int mt = 0; mt < 2; ++mt) {
      float sm[4] = {0.f, 0.f, 0.f, 0.f};
#pragma unroll
      for (int nt = 0; nt < 4; ++nt)
#pragma unroll
        for (int reg = 0; reg < 4; ++reg) {
          float e = fexp2(acc[prow * 8 + mt * 4 + nt][reg]);
          acc[prow * 8 + mt * 4 + nt][reg] = e;
          sm[reg] += e;
        }
#pragma unroll
      for (int reg = 0; reg < 4; ++reg)
        sm[reg] = __builtin_amdgcn_rcpf(sum16(sm[reg]));
#pragma unroll
      for (int nt = 0; nt < 4; ++nt) {
        int idx = (prow * 64 + nt * 16 + b15) * 65 + wc * 32 + mt * 16 + q * 4;
#pragma unroll
        for (int reg = 0; reg < 4; ++reg) {
          float v = acc[prow * 8 + mt * 4 + nt][reg] * sm[reg];
          __hip_atomic_fetch_max((unsigned*)&red[idx + reg], __float_as_uint(v),
                                 __ATOMIC_RELAXED, __HIP_MEMORY_SCOPE_WORKGROUP);
        }
      }
    }
  __syncthreads();

  // ---- coalesced stores ----
  for (int e = tid; e < 4096; e += 512) {
    int pw2  = e & 31;
    int cout = (e >> 5) & 63;
    int rl   = e >> 11;
    int base = (rl * 64 + cout) * 65 + pw2 * 2;
    float2 val = {red[base], red[base + 1]};
    *(float2*)&out[((n * 64 + cout) * 64 + (ph0 + rl)) * 64 + pw2 * 2] = val;
  }
}

extern "C" void kernel_launch(void* const* d_in, const int* in_sizes, int n_in,
                              void* d_out, int out_size, void* d_ws, size_t ws_size,
                              hipStream_t stream) {
  const float* x     = (const float*)d_in[0];
  const float* w     = (const float*)d_in[1];
  const float* bias  = (const float*)d_in[2];
  const float* gamma = (const float*)d_in[3];
  const float* beta  = (const float*)d_in[4];
  const float* mean  = (const float*)d_in[5];
  const float* var   = (const float*)d_in[6];
  float* out = (float*)d_out;

  prep_kernel<<<8, 256, 0, stream>>>(w, bias, gamma, beta, mean, var);
  dim3 grid(32, 32);  // (pooled-row pair [XCD-swizzled], n)
  fused_kernel<<<grid, 512, 0, stream>>>(x, out);
}